// Round 7
// baseline (69.714 us; speedup 1.0000x reference)
//
#include <hip/hip_runtime.h>
#include <hip/hip_bf16.h>

// ObliviousDecisionLayer on MI355X — two-kernel structure, R7 tuning.
// decisions[b,t,d] = rowsum(inputs)[b] * rowsum(dw)[t,d]  (einsum shares no index).
// Leaf fold: bit d of leaf index: 0 -> dec[d], 1 -> 1-dec[d]; /256 folded into leaves.
//
// R7 changes vs R6 (68.9 us):
//  - BPB 8 -> 16: 256 forest blocks, halves table re-read traffic (39->19.5 MB L2).
//  - prep folds -log2(e) into sw_t/th_t so sigmoid = rcp(1 + exp2(fma(...)))
//    using raw v_exp_f32 — one fewer VALU op per sigmoid.
// R5 lesson: do NOT fuse via cooperative grid.sync (+52 us on 256 blocks).

#define NUM_TREES 256
#define DEPTH 6
#define LEAVES 64
#define BATCH 4096
#define FEATURES 256
#define BPB 16  // batch rows per forest block

// ws layout (floats):
#define WS_SWT  0        // [6][256]  sw_t[d][t] = -log2e * rowsum(dw[t][d][:])
#define WS_THT  1536     // [6][256]  th_t[d][t] = -log2e * thr[t][d]
#define WS_B5   3072     // [8][256] float4: B5[c][t] = leaf4[t][c+8] / 256
#define WS_D5   11264    // [8][256] float4: D5[c][t] = (leaf4[t][c]-leaf4[t][c+8]) / 256

#define NEG_LOG2E (-1.4426950408889634f)

// ---------------- Kernel 1: dw row sums + table transposes ----------------
__global__ __launch_bounds__(256) void prep_kernel(
    const float* __restrict__ dw,       // [1536][256]
    const float* __restrict__ thr,      // [256][6]
    const float* __restrict__ leaf,     // [256][64]
    float* __restrict__ ws)
{
    const int gw   = (blockIdx.x * blockDim.x + threadIdx.x) >> 6;
    const int lane = threadIdx.x & 63;
    const float scale = 1.0f / (float)NUM_TREES;

    if (gw < NUM_TREES * DEPTH) {
        const int t = gw / DEPTH;
        const int d = gw - t * DEPTH;
        float4 v = reinterpret_cast<const float4*>(dw + (size_t)gw * FEATURES)[lane];
        float s = (v.x + v.y) + (v.z + v.w);
#pragma unroll
        for (int off = 32; off > 0; off >>= 1)
            s += __shfl_down(s, off);
        if (lane == 0) ws[WS_SWT + d * NUM_TREES + t] = s * NEG_LOG2E;
    } else if (gw < NUM_TREES * DEPTH + 64) {
        // leaf pre-fold: wave j -> chunk c=j>>2 (0..15), trees t=(j&3)*64+lane
        const int j = gw - NUM_TREES * DEPTH;
        const int c = j >> 2;
        const int t = ((j & 3) << 6) | lane;
        const float4* lp = reinterpret_cast<const float4*>(leaf);
        if (c < 8) {
            float4 va = lp[t * (LEAVES / 4) + c];
            float4 vb = lp[t * (LEAVES / 4) + c + 8];
            float4 d;
            d.x = (va.x - vb.x) * scale; d.y = (va.y - vb.y) * scale;
            d.z = (va.z - vb.z) * scale; d.w = (va.w - vb.w) * scale;
            reinterpret_cast<float4*>(ws + WS_D5)[c * NUM_TREES + t] = d;
        } else {
            float4 vb = lp[t * (LEAVES / 4) + c];
            float4 b;
            b.x = vb.x * scale; b.y = vb.y * scale;
            b.z = vb.z * scale; b.w = vb.w * scale;
            reinterpret_cast<float4*>(ws + WS_B5)[(c - 8) * NUM_TREES + t] = b;
        }
    } else {
        // threshold transpose (scaled): 24 waves cover 1536 elements
        const int j = gw - (NUM_TREES * DEPTH + 64);
        const int idx = j * 64 + lane;       // = t*6 + d
        const int t = idx / DEPTH;
        const int d = idx - t * DEPTH;
        ws[WS_THT + d * NUM_TREES + t] = thr[idx] * NEG_LOG2E;
    }
}

// ---------------- Kernel 2: inline row-sums + evaluation + tree-mean ----------------
__global__ __launch_bounds__(256, 1) void forest_kernel(
    const float* __restrict__ inputs,   // [4096][256]
    const float* __restrict__ ws,
    float* __restrict__ out)            // [4096]
{
    const int tid  = threadIdx.x;       // tree index 0..255
    const int lane = tid & 63;
    const int wv   = tid >> 6;
    const int b0   = blockIdx.x * BPB;

    // --- issue all loads up front for ILP ---
    // own-block input rows: wave wv handles rows b0+4wv .. b0+4wv+3
    const float4* ip = reinterpret_cast<const float4*>(inputs);
    const float4 a0 = ip[(size_t)(b0 + 4 * wv + 0) * (FEATURES / 4) + lane];
    const float4 a1 = ip[(size_t)(b0 + 4 * wv + 1) * (FEATURES / 4) + lane];
    const float4 a2 = ip[(size_t)(b0 + 4 * wv + 2) * (FEATURES / 4) + lane];
    const float4 a3 = ip[(size_t)(b0 + 4 * wv + 3) * (FEATURES / 4) + lane];

    // per-tree tables (stride-1 in t, coalesced)
    const int t = tid;
    float sw[DEPTH], th[DEPTH];
#pragma unroll
    for (int d = 0; d < DEPTH; ++d) {
        sw[d] = ws[WS_SWT + d * NUM_TREES + t];
        th[d] = ws[WS_THT + d * NUM_TREES + t];
    }
    float b5[32], d5[32];
#pragma unroll
    for (int c = 0; c < 8; ++c) {
        float4 vb = reinterpret_cast<const float4*>(ws + WS_B5)[c * NUM_TREES + t];
        float4 vd = reinterpret_cast<const float4*>(ws + WS_D5)[c * NUM_TREES + t];
        b5[4 * c + 0] = vb.x; b5[4 * c + 1] = vb.y;
        b5[4 * c + 2] = vb.z; b5[4 * c + 3] = vb.w;
        d5[4 * c + 0] = vd.x; d5[4 * c + 1] = vd.y;
        d5[4 * c + 2] = vd.z; d5[4 * c + 3] = vd.w;
    }

    // --- row sums -> LDS broadcast ---
    float s0 = (a0.x + a0.y) + (a0.z + a0.w);
    float s1 = (a1.x + a1.y) + (a1.z + a1.w);
    float s2 = (a2.x + a2.y) + (a2.z + a2.w);
    float s3 = (a3.x + a3.y) + (a3.z + a3.w);
#pragma unroll
    for (int off = 32; off > 0; off >>= 1) {
        s0 += __shfl_down(s0, off);
        s1 += __shfl_down(s1, off);
        s2 += __shfl_down(s2, off);
        s3 += __shfl_down(s3, off);
    }
    __shared__ float sib[BPB];
    if (lane == 0) {
        sib[4 * wv + 0] = s0; sib[4 * wv + 1] = s1;
        sib[4 * wv + 2] = s2; sib[4 * wv + 3] = s3;
    }
    __syncthreads();

    // --- evaluate BPB rows ---
    float res[BPB];
#pragma unroll
    for (int bi = 0; bi < BPB; ++bi) {
        const float si = sib[bi];            // LDS broadcast (uniform addr)
        float dec[DEPTH];
#pragma unroll
        for (int d = 0; d < DEPTH; ++d) {
            // sigmoid(x) = rcp(1 + exp2(-log2e*x)); -log2e folded into sw/th in prep
            const float e = __builtin_amdgcn_exp2f(fmaf(si, sw[d], th[d]));
            dec[d] = __builtin_amdgcn_rcpf(1.0f + e);
        }
        float m[32];
#pragma unroll
        for (int i = 0; i < 32; ++i) m[i] = fmaf(dec[5], d5[i], b5[i]);
#pragma unroll
        for (int i = 0; i < 16; ++i) m[i] = fmaf(dec[4], m[i] - m[i + 16], m[i + 16]);
#pragma unroll
        for (int i = 0; i < 8; ++i)  m[i] = fmaf(dec[3], m[i] - m[i + 8],  m[i + 8]);
#pragma unroll
        for (int i = 0; i < 4; ++i)  m[i] = fmaf(dec[2], m[i] - m[i + 4],  m[i + 4]);
#pragma unroll
        for (int i = 0; i < 2; ++i)  m[i] = fmaf(dec[1], m[i] - m[i + 2],  m[i + 2]);
        res[bi] = fmaf(dec[0], m[0] - m[1], m[1]);
    }

    // --- reduce over 256 trees (4 waves); 1/256 pre-folded into leaves ---
    __shared__ float red[4][BPB];
#pragma unroll
    for (int bi = 0; bi < BPB; ++bi) {
        float v = res[bi];
#pragma unroll
        for (int off = 32; off > 0; off >>= 1)
            v += __shfl_down(v, off);
        if (lane == 0) red[wv][bi] = v;
    }
    __syncthreads();
    if (tid < BPB) {
        out[b0 + tid] = red[0][tid] + red[1][tid] + red[2][tid] + red[3][tid];
    }
}

extern "C" void kernel_launch(void* const* d_in, const int* in_sizes, int n_in,
                              void* d_out, int out_size, void* d_ws, size_t ws_size,
                              hipStream_t stream) {
    const float* inputs = (const float*)d_in[0];  // [4096][256]
    const float* dw     = (const float*)d_in[1];  // [256][6][256]
    const float* thr    = (const float*)d_in[2];  // [256][6]
    const float* leaf   = (const float*)d_in[3];  // [256][64]
    float* out = (float*)d_out;                   // [4096]
    float* ws  = (float*)d_ws;

    // prep: 1536 + 64 + 24 = 1624 waves, 4 waves/block -> 406 blocks
    prep_kernel<<<406, 256, 0, stream>>>(dw, thr, leaf, ws);

    // forest: 4096 / BPB = 256 blocks of 256 threads
    forest_kernel<<<BATCH / BPB, 256, 0, stream>>>(inputs, ws, out);
}